// Round 6
// baseline (185.312 us; speedup 1.0000x reference)
//
#include <hip/hip_runtime.h>
#include <stdint.h>

#define K_NODES 14
#define C_DIM   512
#define OUT_DIM 512
#define N_EDGE  78

typedef float  f32x4  __attribute__((ext_vector_type(4)));
typedef __bf16 bf16x8 __attribute__((ext_vector_type(8)));

__device__ __forceinline__ unsigned short f2bf(float f) {
    unsigned int u = __builtin_bit_cast(unsigned int, f);
    unsigned int r = (u + 0x7fffu + ((u >> 16) & 1u)) >> 16;  // RNE
    return (unsigned short)r;
}
__device__ __forceinline__ float bf2f(unsigned short s) {
    return __builtin_bit_cast(float, (unsigned int)s << 16);
}

// async 16B global -> LDS (LDS dest is wave-uniform base; HW adds lane*16)
__device__ __forceinline__ void async16(const void* g, void* l) {
    __builtin_amdgcn_global_load_lds(
        (const __attribute__((address_space(1))) unsigned int*)g,
        (__attribute__((address_space(3))) unsigned int*)l, 16, 0, 0);
}

// ------- Kernel 1: per-channel stats partials + x->bf16 + weights->bf16 ----
// 256 blocks x 512 thr; each thread handles TWO samples (more ILP/wave).
__global__ __launch_bounds__(512) void stats_partial(
    const float* __restrict__ x, float* __restrict__ part,
    unsigned short* __restrict__ xbf,
    const float* __restrict__ Wm, const float* __restrict__ Wo,
    unsigned short* __restrict__ wmbf, unsigned short* __restrict__ wobf)
{
    int t  = threadIdx.x;
    int q  = t & 127;           // channel quad: channels 4q..4q+3
    int sn = t >> 7;            // sample slot 0..3
    f32x4 as = (f32x4){0.f,0.f,0.f,0.f};
    f32x4 aq = (f32x4){0.f,0.f,0.f,0.f};

    #pragma unroll
    for (int half = 0; half < 2; ++half) {
        int n = blockIdx.x * 8 + half * 4 + sn;
        size_t base = (size_t)n * K_NODES * C_DIM + q * 4;

        f32x4 g = *(const f32x4*)(x + base + 13 * C_DIM);
        ushort4 gb; gb.x=f2bf(g.x); gb.y=f2bf(g.y); gb.z=f2bf(g.z); gb.w=f2bf(g.w);
        *(ushort4*)(xbf + base + 13 * C_DIM) = gb;

        float S10=0,S11=0,S12=0,S13=0, S20=0,S21=0,S22=0,S23=0, Sw0=0,Sw1=0,Sw2=0,Sw3=0;
        #pragma unroll
        for (int k = 0; k < 13; ++k) {
            f32x4 v = *(const f32x4*)(x + base + k * C_DIM);
            ushort4 vb; vb.x=f2bf(v.x); vb.y=f2bf(v.y); vb.z=f2bf(v.z); vb.w=f2bf(v.w);
            *(ushort4*)(xbf + base + k * C_DIM) = vb;
            float wk = (float)(12 - 2 * k);
            float d0=fabsf(v.x-g.x), d1=fabsf(v.y-g.y), d2=fabsf(v.z-g.z), d3=fabsf(v.w-g.w);
            S10+=d0; S11+=d1; S12+=d2; S13+=d3;
            S20+=d0*d0; S21+=d1*d1; S22+=d2*d2; S23+=d3*d3;
            Sw0+=wk*d0; Sw1+=wk*d1; Sw2+=wk*d2; Sw3+=wk*d3;
        }
        as += (f32x4){15.f*Sw0, 15.f*Sw1, 15.f*Sw2, 15.f*Sw3};
        aq += (f32x4){225.f*(13.f*S20 - S10*S10), 225.f*(13.f*S21 - S11*S11),
                      225.f*(13.f*S22 - S12*S12), 225.f*(13.f*S23 - S13*S13)};
    }

    __shared__ f32x4 redS[4][128];
    __shared__ f32x4 redQ[4][128];
    redS[sn][q] = as;
    redQ[sn][q] = aq;
    __syncthreads();
    if (sn == 0) {
        f32x4 s = redS[0][q], z = redQ[0][q];
        #pragma unroll
        for (int r = 1; r < 4; ++r) { s += redS[r][q]; z += redQ[r][q]; }
        *(f32x4*)(part + (size_t)blockIdx.x * 1024 + q * 4)       = s;
        *(f32x4*)(part + (size_t)blockIdx.x * 1024 + 512 + q * 4) = z;
    }
    int i0 = blockIdx.x * 1024 + t;
    wmbf[i0] = f2bf(Wm[i0]);
    wobf[i0] = f2bf(Wo[i0]);
    wmbf[i0 + 512] = f2bf(Wm[i0 + 512]);
    wobf[i0 + 512] = f2bf(Wo[i0 + 512]);
}

// ---------------- Kernel 2: finalize stats -> u[c], bpart[8] ---------------
__global__ __launch_bounds__(256) void finalize_stats(
    const float* __restrict__ part, float inv_ne,
    const float* __restrict__ gamma, const float* __restrict__ beta,
    const float* __restrict__ wdir, float* __restrict__ u, float* __restrict__ bpart)
{
    int lane = threadIdx.x & 63;
    int wv   = threadIdx.x >> 6;        // 0..3
    int c    = blockIdx.x * 64 + lane;  // channel
    float s = 0.f, q = 0.f;
    #pragma unroll 8
    for (int r = wv; r < 256; r += 4) {
        s += part[(size_t)r * 1024 + c];
        q += part[(size_t)r * 1024 + 512 + c];
    }
    __shared__ float shs[4][64], shq[4][64];
    shs[wv][lane] = s; shq[wv][lane] = q;
    __syncthreads();
    if (wv == 0) {
        s = shs[0][lane] + shs[1][lane] + shs[2][lane] + shs[3][lane];
        q = shq[0][lane] + shq[1][lane] + shq[2][lane] + shq[3][lane];
        float mean = s * inv_ne;
        float var  = q * inv_ne - mean * mean;
        float sc   = gamma[c] / sqrtf(var + 1e-5f);
        u[c] = sc * wdir[c];
        float b = (beta[c] - mean * sc) * wdir[c];
        #pragma unroll
        for (int off = 1; off < 64; off <<= 1) b += __shfl_xor(b, off, 64);
        if (lane == 0) bpart[blockIdx.x] = b;
    }
}

// ---------------- Kernel 3: per-n gates -> normalized W (14x14) ------------
// ONE wave per sample. Writes ONLY wfull[n][i*14+j] = invW[i]*gated_adj
// (1.6 MB total) -- the agg matmul moved into the GEMM epilogue via
// (Wn@x)@Wm^T == Wn@(x@Wm^T).
__global__ __launch_bounds__(256) void fuse_gates(
    const unsigned short* __restrict__ xbf, const float* __restrict__ adj,
    const int* __restrict__ ei, const int* __restrict__ ej,
    const float* __restrict__ u, const float* __restrict__ bpart,
    float* __restrict__ wfull)
{
    __shared__ float WL[4][196];
    __shared__ float Dsh[4][13];
    __shared__ float invW[4][14];
    int wv = threadIdx.x >> 6, lane = threadIdx.x & 63;
    int n  = blockIdx.x * 4 + wv;
    size_t base = (size_t)n * K_NODES * C_DIM + lane * 8;

    // load 14 x-rows (8 bf16 = 16B each) and convert to fp32
    float xf[K_NODES][8];
    #pragma unroll
    for (int k = 0; k < K_NODES; ++k) {
        uint4 raw = *(const uint4*)(xbf + base + k * C_DIM);
        xf[k][0]=bf2f(raw.x&0xffff); xf[k][1]=bf2f(raw.x>>16);
        xf[k][2]=bf2f(raw.y&0xffff); xf[k][3]=bf2f(raw.y>>16);
        xf[k][4]=bf2f(raw.z&0xffff); xf[k][5]=bf2f(raw.z>>16);
        xf[k][6]=bf2f(raw.w&0xffff); xf[k][7]=bf2f(raw.w>>16);
    }
    float uvv[8];
    {
        f32x4 a = *(const f32x4*)(u + lane * 8);
        f32x4 b = *(const f32x4*)(u + lane * 8 + 4);
        uvv[0]=a.x; uvv[1]=a.y; uvv[2]=a.z; uvv[3]=a.w;
        uvv[4]=b.x; uvv[5]=b.y; uvv[6]=b.z; uvv[7]=b.w;
    }

    // D_k = sum_c |x[k][c]-x[13][c]| * u[c]  (full-wave butterfly)
    #pragma unroll
    for (int k = 0; k < 13; ++k) {
        float p = 0.f;
        #pragma unroll
        for (int c = 0; c < 8; ++c) p += fabsf(xf[k][c]-xf[13][c])*uvv[c];
        #pragma unroll
        for (int off = 1; off < 64; off <<= 1) p += __shfl_xor(p, off, 64);
        if (lane == 0) Dsh[wv][k] = p;
    }

    // non-edge entries keep adj value (i==j or i==13 or j==13)
    #pragma unroll
    for (int r = 0; r < 4; ++r) {
        int idx = r * 64 + lane;
        if (idx < K_NODES * K_NODES) {
            int i = idx / K_NODES, j = idx - i * K_NODES;
            if (i == j || i == 13 || j == 13) WL[wv][idx] = adj[idx];
        }
    }
    float bc = 0.f;
    #pragma unroll
    for (int b8 = 0; b8 < 8; ++b8) bc += bpart[b8];
    #pragma unroll
    for (int r = 0; r < 2; ++r) {
        int e = r * 64 + lane;
        if (e < N_EDGE) {
            int ii = ei[e], jj = ej[e];
            float z = 4.0f * (15.f * (Dsh[wv][ii] - Dsh[wv][jj]) + bc);
            float a = 1.f / (1.f + expf(-z));
            WL[wv][ii * K_NODES + jj] = adj[ii * K_NODES + jj] * (2.f * a);
            WL[wv][jj * K_NODES + ii] = adj[jj * K_NODES + ii] * (2.f * (1.f - a));
        }
    }
    if (lane < K_NODES) {
        float s = 0.f;
        #pragma unroll
        for (int j = 0; j < K_NODES; ++j) s += fabsf(WL[wv][lane * K_NODES + j]);
        invW[wv][lane] = 1.f / fmaxf(s, 1e-12f);
    }
    // write normalized W rows (196 floats per sample)
    #pragma unroll
    for (int r = 0; r < 4; ++r) {
        int idx = r * 64 + lane;
        if (idx < 196) {
            int i = idx / K_NODES;
            wfull[(size_t)n * 196 + idx] = WL[wv][idx] * invW[wv][i];
        }
    }
}

// ---------- Kernel 4: Um=x@Wm^T, Uo=x@Wo^T, out=relu(Wn@Um)+Uo -------------
// TM=112 (8 whole samples) x TN=128, 8 waves (512 thr). A staged ONCE per
// K-step for BOTH B matrices (combined A|Bm|Bo region, 368 rows x 64 bf16).
// Wave w owns N-frag w (16 cols) x all 7 M-frags, acc Um[7]+Uo[7].
// Depth-2 double-buffer, one barrier per K-step (R1 schedule).
// Epilogue: Um,Uo -> LDS (reuses staging), wave w mixes sample w with its
// 14x14 Wn (f32, LDS-broadcast), relu, +Uo, store.
#define TM 112
#define TN 128
#define BK 64
#define NROW 368        // 112 A + 128 Bm + 128 Bo
#define NISSUE 46       // NROW/8 (1KB per async16 issue = 8 rows)

__global__ __launch_bounds__(512, 2) void gemm_fused(
    const unsigned short* __restrict__ Axin,
    const unsigned short* __restrict__ Bwm,  const unsigned short* __restrict__ Bwo,
    const float* __restrict__ wfull,
    float* __restrict__ out)
{
    // union: staging 2x47104B (94208) vs epilogue UmL+UoL+wsh (122752)
    __shared__ __align__(16) char smem[122752];
    unsigned short (*lS)[NROW * BK] = (unsigned short (*)[NROW * BK])smem;

    int tid  = threadIdx.x;
    int lane = tid & 63;
    int wave = tid >> 6;            // 0..7 = N-frag
    int bm = blockIdx.x * TM;
    int bn = blockIdx.y * TN;

    // per-lane staging sources (<=6 issues/wave); physical chunk p of LDS
    // row r holds logical chunk p^(r&7) (proven 0-conflict swizzle)
    const unsigned short* gsrc[6];
    #pragma unroll
    for (int k = 0; k < 6; ++k) {
        int q = wave + k * 8;
        if (q < NISSUE) {
            int r   = q * 8 + (lane >> 3);
            int lch = (lane & 7) ^ (r & 7);
            const unsigned short* s;
            if (q < 14)      s = Axin + (size_t)(bm + r) * C_DIM;
            else if (q < 30) s = Bwm  + (size_t)(bn + r - 112) * C_DIM;
            else             s = Bwo  + (size_t)(bn + r - 240) * C_DIM;
            gsrc[k] = s + lch * 8;
        } else gsrc[k] = Axin;
    }

#define STAGE(buf, kb)                                                       \
    _Pragma("unroll")                                                         \
    for (int k = 0; k < 6; ++k)                                               \
        if (wave + k * 8 < NISSUE)                                            \
            async16(gsrc[k] + (kb), &lS[buf][(wave + k * 8) * 512]);

    f32x4 accm[7], acco[7];
    #pragma unroll
    for (int i = 0; i < 7; ++i) {
        accm[i] = (f32x4){0.f,0.f,0.f,0.f};
        acco[i] = (f32x4){0.f,0.f,0.f,0.f};
    }

    int lrow = lane & 15;
    int xorv = lane & 7;

    STAGE(0, 0)
    __syncthreads();

    #pragma unroll
    for (int t = 0; t < 8; ++t) {
        const int cur = t & 1;
        if (t < 7) STAGE(cur ^ 1, (t + 1) * BK)
        #pragma unroll
        for (int ks = 0; ks < 2; ++ks) {
            int pch = ((ks * 4 + (lane >> 4)) ^ xorv) * 8;
            bf16x8 af[7], bmf, bof;
            #pragma unroll
            for (int i = 0; i < 7; ++i)
                af[i] = *(const bf16x8*)&lS[cur][(i * 16 + lrow) * BK + pch];
            bmf = *(const bf16x8*)&lS[cur][(112 + wave * 16 + lrow) * BK + pch];
            bof = *(const bf16x8*)&lS[cur][(240 + wave * 16 + lrow) * BK + pch];
            #pragma unroll
            for (int i = 0; i < 7; ++i) {
                accm[i] = __builtin_amdgcn_mfma_f32_16x16x32_bf16(af[i], bmf, accm[i], 0,0,0);
                acco[i] = __builtin_amdgcn_mfma_f32_16x16x32_bf16(af[i], bof, acco[i], 0,0,0);
            }
        }
        __syncthreads();   // drains prefetch (vmcnt) + closes ds_reads on cur
    }
#undef STAGE

    // ---- epilogue ----
    float (*UmL)[130] = (float (*)[130])smem;                 // [112][130]
    float (*UoL)[130] = (float (*)[130])(smem + 58240);       // [112][130]
    float *wsh        = (float*)(smem + 116480);              // [8][196]

    int q4 = lane >> 4, c15 = lane & 15;
    #pragma unroll
    for (int i = 0; i < 7; ++i)
        #pragma unroll
        for (int r = 0; r < 4; ++r) {
            int row = i * 16 + q4 * 4 + r;
            UmL[row][wave * 16 + c15] = accm[i][r];
            UoL[row][wave * 16 + c15] = acco[i][r];
        }
    for (int idx = tid; idx < 8 * 196; idx += 512)
        wsh[idx] = wfull[(size_t)blockIdx.x * 8 * 196 + idx];
    __syncthreads();

    // wave w mixes sample w: rows 14w..14w+13; lane handles cols lane, lane+64
    float a0[14], a1[14];
    #pragma unroll
    for (int ii = 0; ii < 14; ++ii) { a0[ii] = 0.f; a1[ii] = 0.f; }
    #pragma unroll
    for (int j = 0; j < 14; ++j) {
        float um0 = UmL[wave * 14 + j][lane];
        float um1 = UmL[wave * 14 + j][lane + 64];
        #pragma unroll
        for (int ii = 0; ii < 14; ++ii) {
            float wv_ = wsh[wave * 196 + ii * 14 + j];
            a0[ii] += wv_ * um0;
            a1[ii] += wv_ * um1;
        }
    }
    #pragma unroll
    for (int ii = 0; ii < 14; ++ii) {
        int row = wave * 14 + ii;
        size_t o = (size_t)(bm + row) * OUT_DIM + bn;
        out[o + lane]      = fmaxf(a0[ii], 0.f) + UoL[row][lane];
        out[o + lane + 64] = fmaxf(a1[ii], 0.f) + UoL[row][lane + 64];
    }
}

extern "C" void kernel_launch(void* const* d_in, const int* in_sizes, int n_in,
                              void* d_out, int out_size, void* d_ws, size_t ws_size,
                              hipStream_t stream)
{
    const float* x     = (const float*)d_in[0];
    const float* adj   = (const float*)d_in[1];
    const int*   ei    = (const int*)d_in[2];
    const int*   ej    = (const int*)d_in[3];
    const float* gamma = (const float*)d_in[4];
    const float* beta  = (const float*)d_in[5];
    const float* wdir  = (const float*)d_in[6];
    const float* Wm    = (const float*)d_in[7];
    const float* Wo    = (const float*)d_in[8];
    float* out = (float*)d_out;

    int N = in_sizes[0] / (K_NODES * C_DIM);   // 2048
    int M = N * K_NODES;                        // 28672

    float* ws_f   = (float*)d_ws;
    float* u      = ws_f + 1024;               // [512]
    float* bpart  = ws_f + 1536;               // [8]
    float* part   = ws_f + 2048;               // [256*1024]
    char*  wsb    = (char*)d_ws;
    size_t off    = (size_t)(2048 + 256 * 1024) * sizeof(float);
    unsigned short* wmbf  = (unsigned short*)(wsb + off);  off += (size_t)OUT_DIM * C_DIM * 2;
    unsigned short* wobf  = (unsigned short*)(wsb + off);  off += (size_t)OUT_DIM * C_DIM * 2;
    unsigned short* xbf   = (unsigned short*)(wsb + off);  off += (size_t)M * C_DIM * 2;
    float*          wfull = (float*)(wsb + off);           off += (size_t)N * 196 * 4;

    float inv_ne = 1.0f / ((float)N * (float)N_EDGE);

    hipLaunchKernelGGL(stats_partial, dim3(N / 8), dim3(512), 0, stream,
                       x, part, xbf, Wm, Wo, wmbf, wobf);
    hipLaunchKernelGGL(finalize_stats, dim3(8), dim3(256), 0, stream,
                       part, inv_ne, gamma, beta, wdir, u, bpart);
    hipLaunchKernelGGL(fuse_gates, dim3(N / 4), dim3(256), 0, stream,
                       xbf, adj, ei, ej, u, bpart, wfull);
    hipLaunchKernelGGL(gemm_fused, dim3(M / TM, OUT_DIM / TN), dim3(512), 0, stream,
                       xbf, wmbf, wobf, wfull, out);
}